// Round 1
// baseline (411.529 us; speedup 1.0000x reference)
//
#include <hip/hip_runtime.h>

#define D        128
#define N_GRAPHS 64
#define N_CLS    16
#define LDA      40   // mm1m LDS row stride in bf16 (80 B: 16B-aligned, 2-way banks = free)
#define SLOTS    48   // padded CSR width; deg ~ Poisson(16), P(>48) ~ 1e-11
#define CAP      8192 // bucket capacity (avg 4096, std ~64 -> 2x margin)
#define NCH      768  // S2 contraction chunks; P = NCH*64*128*4B = 25.2 MB (aliases nbb)

typedef unsigned int   uint;
typedef unsigned short ushort;
typedef __attribute__((ext_vector_type(8))) short short8;
typedef __attribute__((ext_vector_type(4))) float f32x4;

__device__ inline ushort f2b(float f) {   // f32 -> bf16 RNE
    uint u = __float_as_uint(f);
    u += 0x7fffu + ((u >> 16) & 1u);
    return (ushort)(u >> 16);
}

// ---------------- phase A: partition edges into 256-node buckets ------------

__global__ __launch_bounds__(256) void k_part(
    const int* __restrict__ src, const int* __restrict__ dst,
    int* __restrict__ bcount, uint* __restrict__ ebuf, int E, int NB) {
    __shared__ int hist[512], base[512], lcur[512];
    int t = threadIdx.x;
    int per = (E + gridDim.x - 1) / gridDim.x;
    int e0 = blockIdx.x * per;
    int e1 = min(e0 + per, E);
    for (int i = t; i < NB; i += 256) { hist[i] = 0; lcur[i] = 0; }
    __syncthreads();
    for (int e = e0 + t; e < e1; e += 256) atomicAdd(&hist[dst[e] >> 8], 1);
    __syncthreads();
    for (int i = t; i < NB; i += 256)
        base[i] = hist[i] ? atomicAdd(&bcount[i], hist[i]) : 0;
    __syncthreads();
    for (int e = e0 + t; e < e1; e += 256) {
        int dd = dst[e];
        int b = dd >> 8;
        int off = atomicAdd(&lcur[b], 1);
        int pos = base[b] + off;
        if (pos < CAP)
            ebuf[(size_t)b * CAP + pos] = ((uint)src[e] << 8) | (uint)(dd & 255);
    }
}

// ---------------- phase B: per-bucket CSR slice in LDS, linear flush --------

__global__ __launch_bounds__(1024) void k_bucket(
    const uint* __restrict__ ebuf, const int* __restrict__ bcount,
    int* __restrict__ csrf, int* __restrict__ deg, float* __restrict__ invdeg,
    int N) {
    __shared__ int ldeg[256];
    __shared__ int lcsr[256 * SLOTS];
    int b = blockIdx.x, t = threadIdx.x;
    if (t < 256) ldeg[t] = 0;
    __syncthreads();
    int cnt = bcount[b];
    if (cnt > CAP) cnt = CAP;
    const uint* __restrict__ eb = ebuf + (size_t)b * CAP;
    for (int i = t; i < cnt; i += 1024) {
        uint r = eb[i];
        int dl = r & 255;
        int sl = atomicAdd(&ldeg[dl], 1);
        if (sl < SLOTS) lcsr[dl * SLOTS + sl] = (int)(r >> 8);
    }
    __syncthreads();
    int n0 = b << 8;
    int lim = (N - n0) * SLOTS;
    if (lim > 256 * SLOTS) lim = 256 * SLOTS;
    for (int i = t; i < lim; i += 1024)
        csrf[(size_t)n0 * SLOTS + i] = lcsr[i];
    if (t < 256 && n0 + t < N) {
        int d = ldeg[t];
        deg[n0 + t] = d;
        invdeg[n0 + t] = 1.0f / (float)(d > 1 ? d : 1);
    }
}

// graph boundaries from sorted gid: gstart[g] = lower_bound(gid, g)
__global__ void k_gbound(const int* __restrict__ gid, int* __restrict__ gstart, int N) {
    int g = threadIdx.x;
    if (g > N_GRAPHS) return;
    int lo = 0, hi = N;
    while (lo < hi) {
        int mid = (lo + hi) >> 1;
        if (gid[mid] < g) lo = mid + 1; else hi = mid;
    }
    gstart[g] = lo;
}

// ---------------- casts ----------------

__global__ void k_cast(const float* __restrict__ x, ushort* __restrict__ y, int total4) {
    int i = blockIdx.x * 256 + threadIdx.x;
    if (i < total4) {
        float4 v = ((const float4*)x)[i];
        ushort4 o;
        o.x = f2b(v.x); o.y = f2b(v.y); o.z = f2b(v.z); o.w = f2b(v.w);
        ((ushort4*)y)[i] = o;
    }
}

// wT[col][k] (k=0..255: Ws rows then Wn rows), bf16
__global__ void k_castw(const float* __restrict__ Ws, const float* __restrict__ Wn,
                        ushort* __restrict__ wT) {
    int i = blockIdx.x * 256 + threadIdx.x;   // 32768
    int c = i >> 8, k = i & 255;
    float v = (k < 128) ? Ws[k * 128 + c] : Wn[(k - 128) * 128 + c];
    wT[c * 256 + k] = f2b(v);
}

// ---------------- bf16 neighbor-mean gather: wave per node (full 256B rows) --

__global__ __launch_bounds__(256) void k_aggb(
    const ushort* __restrict__ fb, const int* __restrict__ deg,
    const int* __restrict__ csrf, const float* __restrict__ invdeg,
    ushort* __restrict__ outb, int N) {
    int lane = threadIdx.x & 63;
    int n = blockIdx.x * 4 + (threadIdx.x >> 6);
    if (n >= N) return;
    int d = deg[n];
    if (d > SLOTS) d = SLOTS;
    const int* __restrict__ lst = csrf + (size_t)n * SLOTS;
    int ej = lane >> 4;      // 0..3
    int cg = lane & 15;      // cols cg*8 .. cg*8+7

    float acc[8];
#pragma unroll
    for (int i = 0; i < 8; i++) acc[i] = 0.f;

    int e = ej;
    for (; e + 4 < d; e += 8) {
        int s0 = lst[e];
        int s1 = lst[e + 4];
        uint4 v0 = *(const uint4*)(fb + (size_t)s0 * D + cg * 8);
        uint4 v1 = *(const uint4*)(fb + (size_t)s1 * D + cg * 8);
        acc[0] += __uint_as_float(v0.x << 16);
        acc[1] += __uint_as_float(v0.x & 0xffff0000u);
        acc[2] += __uint_as_float(v0.y << 16);
        acc[3] += __uint_as_float(v0.y & 0xffff0000u);
        acc[4] += __uint_as_float(v0.z << 16);
        acc[5] += __uint_as_float(v0.z & 0xffff0000u);
        acc[6] += __uint_as_float(v0.w << 16);
        acc[7] += __uint_as_float(v0.w & 0xffff0000u);
        acc[0] += __uint_as_float(v1.x << 16);
        acc[1] += __uint_as_float(v1.x & 0xffff0000u);
        acc[2] += __uint_as_float(v1.y << 16);
        acc[3] += __uint_as_float(v1.y & 0xffff0000u);
        acc[4] += __uint_as_float(v1.z << 16);
        acc[5] += __uint_as_float(v1.z & 0xffff0000u);
        acc[6] += __uint_as_float(v1.w << 16);
        acc[7] += __uint_as_float(v1.w & 0xffff0000u);
    }
    for (; e < d; e += 4) {
        int s = lst[e];
        uint4 v = *(const uint4*)(fb + (size_t)s * D + cg * 8);
        acc[0] += __uint_as_float(v.x << 16);
        acc[1] += __uint_as_float(v.x & 0xffff0000u);
        acc[2] += __uint_as_float(v.y << 16);
        acc[3] += __uint_as_float(v.y & 0xffff0000u);
        acc[4] += __uint_as_float(v.z << 16);
        acc[5] += __uint_as_float(v.z & 0xffff0000u);
        acc[6] += __uint_as_float(v.w << 16);
        acc[7] += __uint_as_float(v.w & 0xffff0000u);
    }
#pragma unroll
    for (int i = 0; i < 8; i++) {
        acc[i] += __shfl_xor(acc[i], 16);
        acc[i] += __shfl_xor(acc[i], 32);
    }
    if (ej == 0) {
        float id = invdeg[n];
        uint4 o;
        o.x = (uint)f2b(acc[0] * id) | ((uint)f2b(acc[1] * id) << 16);
        o.y = (uint)f2b(acc[2] * id) | ((uint)f2b(acc[3] * id) << 16);
        o.z = (uint)f2b(acc[4] * id) | ((uint)f2b(acc[5] * id) << 16);
        o.w = (uint)f2b(acc[6] * id) | ((uint)f2b(acc[7] * id) << 16);
        *(uint4*)(outb + (size_t)n * D + cg * 8) = o;
    }
}

// ---------------- layer-1 GEMM via MFMA (bf16 in, bf16 out) ----------------

__global__ __launch_bounds__(256, 2) void k_mm1m(
    const ushort* __restrict__ hb, const ushort* __restrict__ nbb,
    const ushort* __restrict__ wT, const float* __restrict__ b,
    ushort* __restrict__ x1b, int N) {
    __shared__ __align__(16) ushort As[128 * LDA];
    __shared__ __align__(16) ushort Bs[128 * LDA];
    int t    = threadIdx.x;
    int w    = t >> 6;
    int lane = t & 63;
    int m    = lane & 15;
    int quad = lane >> 4;
    int n0   = blockIdx.x * 128;

    f32x4 acc[2][8];
#pragma unroll
    for (int rt = 0; rt < 2; rt++)
#pragma unroll
        for (int ct = 0; ct < 8; ct++) acc[rt][ct] = (f32x4){0.f, 0.f, 0.f, 0.f};

#pragma unroll 1
    for (int kc = 0; kc < 8; kc++) {
        int k0 = kc * 32;
        const ushort* __restrict__ A = (k0 < 128) ? hb : nbb;
        int ka = k0 & 127;
        __syncthreads();
#pragma unroll
        for (int i = 0; i < 2; i++) {
            int linear = i * 256 + t;       // 0..511
            int row = linear >> 2;
            int q   = linear & 3;
            int nn = n0 + row;
            uint4 v = make_uint4(0u, 0u, 0u, 0u);
            if (nn < N) v = *(const uint4*)(A + (size_t)nn * D + ka + q * 8);
            *(uint4*)(&As[row * LDA + q * 8]) = v;
        }
#pragma unroll
        for (int i = 0; i < 2; i++) {
            int linear = i * 256 + t;
            int col = linear >> 2;
            int q   = linear & 3;
            uint4 v = *(const uint4*)(wT + (size_t)col * 256 + k0 + q * 8);
            *(uint4*)(&Bs[col * LDA + q * 8]) = v;
        }
        __syncthreads();
        short8 af[2], bf[8];
#pragma unroll
        for (int rt = 0; rt < 2; rt++)
            af[rt] = *(const short8*)(&As[(w * 32 + rt * 16 + m) * LDA + quad * 8]);
#pragma unroll
        for (int ct = 0; ct < 8; ct++)
            bf[ct] = *(const short8*)(&Bs[(ct * 16 + m) * LDA + quad * 8]);
#pragma unroll
        for (int rt = 0; rt < 2; rt++)
#pragma unroll
            for (int ct = 0; ct < 8; ct++)
                acc[rt][ct] = __builtin_amdgcn_mfma_f32_16x16x32_bf16(
                    af[rt], bf[ct], acc[rt][ct], 0, 0, 0);
    }
#pragma unroll
    for (int ct = 0; ct < 8; ct++) {
        float bias = b[ct * 16 + m];
#pragma unroll
        for (int rt = 0; rt < 2; rt++) {
#pragma unroll
            for (int r = 0; r < 4; r++) {
                int n = n0 + w * 32 + rt * 16 + quad * 4 + r;
                if (n < N)
                    x1b[(size_t)n * D + ct * 16 + m] =
                        f2b(fmaxf(acc[rt][ct][r] + bias, 0.f));
            }
        }
    }
}

// ---------------- layer-2 neigh sum, algebraically collapsed ----------------
// S2[g] = sum_{edges e: dst in g} invdeg[dst] * x1[src]
//       = sum_n x1[n] * W[n,g],  W[n,g] = sum_{e: src=n} invdeg[dst]*[gid(dst)=g]
// Build W with 8 B/edge lookups (gid/invdeg are 800 KB, L2-resident) + one
// scattered f32 atomic per edge -- replaces the 410 MB x1-row gather.

__global__ __launch_bounds__(256) void k_wcoef(
    const int* __restrict__ src, const int* __restrict__ dst,
    const int* __restrict__ gid, const float* __restrict__ invdeg,
    float* __restrict__ wc, int E) {
    int i = blockIdx.x * 256 + threadIdx.x;
    if (i >= E) return;
    int s = src[i];
    int d = dst[i];
    atomicAdd(&wc[(size_t)s * 64 + gid[d]], invdeg[d]);
}

// dense contraction S2_partial[chunk] = sum_{n in chunk} W[n,:]^T x1[n,:]
// block = 256 threads; wave w owns graph block [w*16, w*16+16); lane owns
// col pair 2*(t&63). W-row reads from LDS are wave-uniform (broadcast, free);
// x1 reads are 2-way bank aliased (free). 32 f32 acc regs/thread.
__global__ __launch_bounds__(256) void k_s2(
    const float* __restrict__ wc, const ushort* __restrict__ x1b,
    float* __restrict__ P, int N) {
    __shared__ float wl[4][64];
    __shared__ uint  xl[4][64];
    const uint* __restrict__ x1u = (const uint*)x1b;
    int t  = threadIdx.x;
    int gq = t >> 6;          // wave id = g-block, also node-load index
    int cp = t & 63;          // col pair -> cols 2*cp, 2*cp+1
    int chunk = blockIdx.x;
    int a = (int)(((long long)chunk * N) / NCH);
    int b = (int)(((long long)(chunk + 1) * N) / NCH);

    float acc[16][2];
#pragma unroll
    for (int g = 0; g < 16; g++) { acc[g][0] = 0.f; acc[g][1] = 0.f; }

    for (int n0 = a; n0 < b; n0 += 4) {
        int n = n0 + gq;
        bool ok = n < b;
        wl[gq][cp] = ok ? wc[(size_t)n * 64 + cp] : 0.f;
        xl[gq][cp] = ok ? x1u[(size_t)n * 64 + cp] : 0u;
        __syncthreads();
#pragma unroll
        for (int nn = 0; nn < 4; nn++) {
            uint xv = xl[nn][cp];
            float x0 = __uint_as_float(xv << 16);
            float x1 = __uint_as_float(xv & 0xffff0000u);
#pragma unroll
            for (int gg = 0; gg < 16; gg++) {
                float wv = wl[nn][gq * 16 + gg];
                acc[gg][0] = fmaf(wv, x0, acc[gg][0]);
                acc[gg][1] = fmaf(wv, x1, acc[gg][1]);
            }
        }
        __syncthreads();
    }
    float2* __restrict__ Pp = (float2*)(P + (size_t)chunk * 8192);
#pragma unroll
    for (int gg = 0; gg < 16; gg++)
        Pp[(gq * 16 + gg) * 64 + cp] = make_float2(acc[gg][0], acc[gg][1]);
}

// reduce partials: S2[i] += sum_ch P[ch][i]; grid (32, 8), S2 pre-zeroed
__global__ __launch_bounds__(256) void k_s2red(
    const float* __restrict__ P, float* __restrict__ S2) {
    int i = blockIdx.x * 256 + threadIdx.x;     // 0..8191
    int c0 = blockIdx.y * (NCH / 8);
    float s = 0.f;
#pragma unroll 8
    for (int ch = 0; ch < NCH / 8; ch++)
        s += P[(size_t)(c0 + ch) * 8192 + i];
    atomicAdd(&S2[i], s);
}

// ---------------- per-graph x1 sums (contiguous ranges via gstart) ----------

__global__ __launch_bounds__(256) void k_gsum1(
    const ushort* __restrict__ x1b, const int* __restrict__ gstart,
    float* __restrict__ S1) {
    int g  = blockIdx.x >> 3;
    int ch = blockIdx.x & 7;
    int r0 = gstart[g], r1 = gstart[g + 1];
    int len = r1 - r0;
    if (len <= 0) return;
    int L = (len + 7) >> 3;
    int a = r0 + ch * L;
    int bnd = min(a + L, r1);
    if (a >= bnd) return;

    int rp = threadIdx.x >> 6;    // 0..3 row phase
    int cp = threadIdx.x & 63;    // col pair
    float ax = 0.f, ay = 0.f;
    const uint* __restrict__ M = (const uint*)x1b;
    for (int n = a + rp; n < bnd; n += 4) {
        uint v = M[(size_t)n * 64 + cp];
        ax += __uint_as_float(v << 16);
        ay += __uint_as_float(v & 0xffff0000u);
    }
    atomicAdd(&S1[g * D + cp * 2], ax);
    atomicAdd(&S1[g * D + cp * 2 + 1], ay);
}

// ---------------- final: hg = (S1@W2s + S2@W2n)/cnt + b2 ; out = hg@Wc + bc ----

__global__ void k_final(const float* __restrict__ S1, const float* __restrict__ S2,
                        const int* __restrict__ gstart, const float* __restrict__ W2s,
                        const float* __restrict__ W2n, const float* __restrict__ b2,
                        const float* __restrict__ Wc, const float* __restrict__ bc,
                        float* __restrict__ out) {
    __shared__ float s1[D], s2[D], hg[D];
    int g = blockIdx.x, c = threadIdx.x;
    s1[c] = S1[g * D + c];
    s2[c] = S2[g * D + c];
    __syncthreads();
    float acc = 0.f;
#pragma unroll 8
    for (int k = 0; k < D; k++) {
        acc = fmaf(s1[k], W2s[k * D + c], acc);
        acc = fmaf(s2[k], W2n[k * D + c], acc);
    }
    int cnt = gstart[g + 1] - gstart[g];
    hg[c] = (cnt > 0) ? (acc / (float)cnt + b2[c]) : 0.f;
    __syncthreads();
    if (c < N_CLS) {
        float o = bc[c];
        for (int k = 0; k < D; k++) o = fmaf(hg[k], Wc[k * N_CLS + c], o);
        out[g * N_CLS + c] = o;
    }
}

// ---------------- launch ----------------

extern "C" void kernel_launch(void* const* d_in, const int* in_sizes, int n_in,
                              void* d_out, int out_size, void* d_ws, size_t ws_size,
                              hipStream_t stream) {
    const float* h   = (const float*)d_in[0];
    const int*   src = (const int*)d_in[1];
    const int*   dst = (const int*)d_in[2];
    const int*   gid = (const int*)d_in[3];
    const float* W1s = (const float*)d_in[5];
    const float* W1n = (const float*)d_in[6];
    const float* b1  = (const float*)d_in[7];
    const float* W2s = (const float*)d_in[8];
    const float* W2n = (const float*)d_in[9];
    const float* b2  = (const float*)d_in[10];
    const float* Wc  = (const float*)d_in[11];
    const float* bc  = (const float*)d_in[12];
    float* out = (float*)d_out;

    const int N = in_sizes[0] / D;  // 100000
    const int E = in_sizes[1];      // 1600000
    const int NB = (N + 255) >> 8;  // 391 buckets

    char* w = (char*)d_ws;
    size_t off = 0;
    auto alloc = [&](size_t elems) -> void* {   // elems are 4-byte units
        void* p = w + off;
        off += elems * 4;
        return p;
    };
    // zero-initialized region first (one memset)
    float* S1     = (float*)alloc((size_t)N_GRAPHS * D);
    float* S2     = (float*)alloc((size_t)N_GRAPHS * D);
    int*   bcount = (int*)alloc(512);
    size_t zero_bytes = off;
    int*   deg    = (int*)alloc(N);
    float* invdeg = (float*)alloc(N);
    int*   gstart = (int*)alloc(128);
    int*   csrf   = (int*)alloc((size_t)N * SLOTS);   // 19.2 MB padded CSR
    ushort* fb    = (ushort*)alloc((size_t)N * 64);   // bf16 [N,128] h
    ushort* nbb   = (ushort*)alloc((size_t)N * 64);   // bf16 [N,128] neigh1
    ushort* x1b   = (ushort*)alloc((size_t)N * 64);   // bf16 [N,128] x1
    ushort* wT    = (ushort*)alloc(16384);            // bf16 [128 cols][256 k]
    // aliases (dead-buffer reuse, no workspace growth):
    uint*  ebuf  = (uint*)nbb;   // edge buckets: dead once k_aggb writes nbb
    float* wcoef = (float*)fb;   // [N,64] f32 coeffs: fb dead after k_mm1m
    float* P     = (float*)nbb;  // [NCH,64,128] f32 partials: nbb dead after k_mm1m
    (void)ws_size; (void)csrf;

    hipMemsetAsync(d_ws, 0, zero_bytes, stream);

    int t4  = N * 32;  // float4 count of [N,128] f32

    k_cast<<<(t4 + 255) / 256, 256, 0, stream>>>(h, fb, t4);
    k_castw<<<128, 256, 0, stream>>>(W1s, W1n, wT);
    k_part<<<256, 256, 0, stream>>>(src, dst, bcount, ebuf, E, NB);
    k_bucket<<<NB, 1024, 0, stream>>>(ebuf, bcount, csrf, deg, invdeg, N);
    k_gbound<<<1, 128, 0, stream>>>(gid, gstart, N);
    k_aggb<<<(N + 3) / 4, 256, 0, stream>>>(fb, deg, csrf, invdeg, nbb, N);
    k_mm1m<<<(N + 127) / 128, 256, 0, stream>>>(fb, nbb, wT, b1, x1b, N);
    // fb and nbb are now dead: build layer-2 coefficient matrix + contraction
    hipMemsetAsync(wcoef, 0, (size_t)N * 64 * sizeof(float), stream);
    k_wcoef<<<(E + 255) / 256, 256, 0, stream>>>(src, dst, gid, invdeg, wcoef, E);
    k_s2<<<NCH, 256, 0, stream>>>(wcoef, x1b, P, N);
    k_s2red<<<dim3(32, 8), 256, 0, stream>>>(P, S2);
    k_gsum1<<<N_GRAPHS * 8, 256, 0, stream>>>(x1b, gstart, S1);
    k_final<<<N_GRAPHS, 128, 0, stream>>>(S1, S2, gstart, W2s, W2n, b2, Wc, bc, out);
}

// Round 2
// 375.870 us; speedup vs baseline: 1.0949x; 1.0949x over previous
//
#include <hip/hip_runtime.h>

#define D        128
#define N_GRAPHS 64
#define N_CLS    16
#define LDA      40   // mm1m LDS row stride in bf16 (80 B: 16B-aligned, 2-way banks = free)
#define SLOTS    48   // padded CSR width; deg ~ Poisson(16), P(>48) ~ 1e-11
#define CAP      8192 // bucket capacity (avg 4096, std ~64 -> 2x margin)
#define NCH      768  // S2 contraction chunks; P = NCH*64*128*4B = 25.2 MB (aliases nbb)

typedef unsigned int   uint;
typedef unsigned short ushort;
typedef __attribute__((ext_vector_type(8))) short short8;
typedef __attribute__((ext_vector_type(4))) float f32x4;

__device__ inline ushort f2b(float f) {   // f32 -> bf16 RNE
    uint u = __float_as_uint(f);
    u += 0x7fffu + ((u >> 16) & 1u);
    return (ushort)(u >> 16);
}

// ---------------- phase A: partition edges into 256-node buckets (by dst) ---

__global__ __launch_bounds__(256) void k_part(
    const int* __restrict__ src, const int* __restrict__ dst,
    int* __restrict__ bcount, uint* __restrict__ ebuf, int E, int NB) {
    __shared__ int hist[512], base[512], lcur[512];
    int t = threadIdx.x;
    int per = (E + gridDim.x - 1) / gridDim.x;
    int e0 = blockIdx.x * per;
    int e1 = min(e0 + per, E);
    for (int i = t; i < NB; i += 256) { hist[i] = 0; lcur[i] = 0; }
    __syncthreads();
    for (int e = e0 + t; e < e1; e += 256) atomicAdd(&hist[dst[e] >> 8], 1);
    __syncthreads();
    for (int i = t; i < NB; i += 256)
        base[i] = hist[i] ? atomicAdd(&bcount[i], hist[i]) : 0;
    __syncthreads();
    for (int e = e0 + t; e < e1; e += 256) {
        int dd = dst[e];
        int b = dd >> 8;
        int off = atomicAdd(&lcur[b], 1);
        int pos = base[b] + off;
        if (pos < CAP)
            ebuf[(size_t)b * CAP + pos] = ((uint)src[e] << 8) | (uint)(dd & 255);
    }
}

// ---- same, by src; record = (dst<<8)|(src&255) (dst<2^17 -> 25 bits) ------

__global__ __launch_bounds__(256) void k_part2(
    const int* __restrict__ src, const int* __restrict__ dst,
    int* __restrict__ bcount2, uint* __restrict__ ebuf2, int E, int NB) {
    __shared__ int hist[512], base[512], lcur[512];
    int t = threadIdx.x;
    int per = (E + gridDim.x - 1) / gridDim.x;
    int e0 = blockIdx.x * per;
    int e1 = min(e0 + per, E);
    for (int i = t; i < NB; i += 256) { hist[i] = 0; lcur[i] = 0; }
    __syncthreads();
    for (int e = e0 + t; e < e1; e += 256) atomicAdd(&hist[src[e] >> 8], 1);
    __syncthreads();
    for (int i = t; i < NB; i += 256)
        base[i] = hist[i] ? atomicAdd(&bcount2[i], hist[i]) : 0;
    __syncthreads();
    for (int e = e0 + t; e < e1; e += 256) {
        int ss = src[e];
        int b = ss >> 8;
        int off = atomicAdd(&lcur[b], 1);
        int pos = base[b] + off;
        if (pos < CAP)
            ebuf2[(size_t)b * CAP + pos] = ((uint)dst[e] << 8) | (uint)(ss & 255);
    }
}

// ---------------- phase B: per-bucket CSR slice in LDS, linear flush --------

__global__ __launch_bounds__(1024) void k_bucket(
    const uint* __restrict__ ebuf, const int* __restrict__ bcount,
    int* __restrict__ csrf, int* __restrict__ deg, float* __restrict__ invdeg,
    int N) {
    __shared__ int ldeg[256];
    __shared__ int lcsr[256 * SLOTS];
    int b = blockIdx.x, t = threadIdx.x;
    if (t < 256) ldeg[t] = 0;
    __syncthreads();
    int cnt = bcount[b];
    if (cnt > CAP) cnt = CAP;
    const uint* __restrict__ eb = ebuf + (size_t)b * CAP;
    for (int i = t; i < cnt; i += 1024) {
        uint r = eb[i];
        int dl = r & 255;
        int sl = atomicAdd(&ldeg[dl], 1);
        if (sl < SLOTS) lcsr[dl * SLOTS + sl] = (int)(r >> 8);
    }
    __syncthreads();
    int n0 = b << 8;
    int lim = (N - n0) * SLOTS;
    if (lim > 256 * SLOTS) lim = 256 * SLOTS;
    for (int i = t; i < lim; i += 1024)
        csrf[(size_t)n0 * SLOTS + i] = lcsr[i];
    if (t < 256 && n0 + t < N) {
        int d = ldeg[t];
        deg[n0 + t] = d;
        invdeg[n0 + t] = 1.0f / (float)(d > 1 ? d : 1);
    }
}

// ---- layer-2 coefficient build: per-src-bucket LDS accumulate + linear flush
// wcoef[s][g] = sum_{e: src=s} invdeg[dst]*[gid(dst)=g]; slice = 64 KB LDS.
// gid/invdeg lookups are random 4B within 800 KB (L2-resident). LDS atomic
// bank = g mod 32, g uniform-random -> ~2-way aliasing (free, m136).

__global__ __launch_bounds__(1024) void k_wbucket(
    const uint* __restrict__ ebuf2, const int* __restrict__ bcount2,
    const int* __restrict__ gid, const float* __restrict__ invdeg,
    float* __restrict__ wc, int N) {
    __shared__ float lwc[256 * 64];   // 64 KB
    int b = blockIdx.x, t = threadIdx.x;
    for (int i = t; i < 256 * 64; i += 1024) lwc[i] = 0.f;
    __syncthreads();
    int cnt = bcount2[b];
    if (cnt > CAP) cnt = CAP;
    const uint* __restrict__ eb = ebuf2 + (size_t)b * CAP;
    for (int i = t; i < cnt; i += 1024) {
        uint r = eb[i];
        int d  = (int)(r >> 8);
        int sl = (int)(r & 255u);
        atomicAdd(&lwc[sl * 64 + gid[d]], invdeg[d]);
    }
    __syncthreads();
    int n0 = b << 8;
    int lim = (N - n0) < 256 ? (N - n0) * 64 : 256 * 64;
    for (int i = t; i < lim; i += 1024)
        wc[(size_t)n0 * 64 + i] = lwc[i];
}

// graph boundaries from sorted gid: gstart[g] = lower_bound(gid, g)
__global__ void k_gbound(const int* __restrict__ gid, int* __restrict__ gstart, int N) {
    int g = threadIdx.x;
    if (g > N_GRAPHS) return;
    int lo = 0, hi = N;
    while (lo < hi) {
        int mid = (lo + hi) >> 1;
        if (gid[mid] < g) lo = mid + 1; else hi = mid;
    }
    gstart[g] = lo;
}

// ---------------- casts ----------------

__global__ void k_cast(const float* __restrict__ x, ushort* __restrict__ y, int total4) {
    int i = blockIdx.x * 256 + threadIdx.x;
    if (i < total4) {
        float4 v = ((const float4*)x)[i];
        ushort4 o;
        o.x = f2b(v.x); o.y = f2b(v.y); o.z = f2b(v.z); o.w = f2b(v.w);
        ((ushort4*)y)[i] = o;
    }
}

// wT[col][k] (k=0..255: Ws rows then Wn rows), bf16
__global__ void k_castw(const float* __restrict__ Ws, const float* __restrict__ Wn,
                        ushort* __restrict__ wT) {
    int i = blockIdx.x * 256 + threadIdx.x;   // 32768
    int c = i >> 8, k = i & 255;
    float v = (k < 128) ? Ws[k * 128 + c] : Wn[(k - 128) * 128 + c];
    wT[c * 256 + k] = f2b(v);
}

// ---------------- bf16 neighbor-mean gather: wave per node (full 256B rows) --

__global__ __launch_bounds__(256) void k_aggb(
    const ushort* __restrict__ fb, const int* __restrict__ deg,
    const int* __restrict__ csrf, const float* __restrict__ invdeg,
    ushort* __restrict__ outb, int N) {
    int lane = threadIdx.x & 63;
    int n = blockIdx.x * 4 + (threadIdx.x >> 6);
    if (n >= N) return;
    int d = deg[n];
    if (d > SLOTS) d = SLOTS;
    const int* __restrict__ lst = csrf + (size_t)n * SLOTS;
    int ej = lane >> 4;      // 0..3
    int cg = lane & 15;      // cols cg*8 .. cg*8+7

    float acc[8];
#pragma unroll
    for (int i = 0; i < 8; i++) acc[i] = 0.f;

    int e = ej;
    for (; e + 4 < d; e += 8) {
        int s0 = lst[e];
        int s1 = lst[e + 4];
        uint4 v0 = *(const uint4*)(fb + (size_t)s0 * D + cg * 8);
        uint4 v1 = *(const uint4*)(fb + (size_t)s1 * D + cg * 8);
        acc[0] += __uint_as_float(v0.x << 16);
        acc[1] += __uint_as_float(v0.x & 0xffff0000u);
        acc[2] += __uint_as_float(v0.y << 16);
        acc[3] += __uint_as_float(v0.y & 0xffff0000u);
        acc[4] += __uint_as_float(v0.z << 16);
        acc[5] += __uint_as_float(v0.z & 0xffff0000u);
        acc[6] += __uint_as_float(v0.w << 16);
        acc[7] += __uint_as_float(v0.w & 0xffff0000u);
        acc[0] += __uint_as_float(v1.x << 16);
        acc[1] += __uint_as_float(v1.x & 0xffff0000u);
        acc[2] += __uint_as_float(v1.y << 16);
        acc[3] += __uint_as_float(v1.y & 0xffff0000u);
        acc[4] += __uint_as_float(v1.z << 16);
        acc[5] += __uint_as_float(v1.z & 0xffff0000u);
        acc[6] += __uint_as_float(v1.w << 16);
        acc[7] += __uint_as_float(v1.w & 0xffff0000u);
    }
    for (; e < d; e += 4) {
        int s = lst[e];
        uint4 v = *(const uint4*)(fb + (size_t)s * D + cg * 8);
        acc[0] += __uint_as_float(v.x << 16);
        acc[1] += __uint_as_float(v.x & 0xffff0000u);
        acc[2] += __uint_as_float(v.y << 16);
        acc[3] += __uint_as_float(v.y & 0xffff0000u);
        acc[4] += __uint_as_float(v.z << 16);
        acc[5] += __uint_as_float(v.z & 0xffff0000u);
        acc[6] += __uint_as_float(v.w << 16);
        acc[7] += __uint_as_float(v.w & 0xffff0000u);
    }
#pragma unroll
    for (int i = 0; i < 8; i++) {
        acc[i] += __shfl_xor(acc[i], 16);
        acc[i] += __shfl_xor(acc[i], 32);
    }
    if (ej == 0) {
        float id = invdeg[n];
        uint4 o;
        o.x = (uint)f2b(acc[0] * id) | ((uint)f2b(acc[1] * id) << 16);
        o.y = (uint)f2b(acc[2] * id) | ((uint)f2b(acc[3] * id) << 16);
        o.z = (uint)f2b(acc[4] * id) | ((uint)f2b(acc[5] * id) << 16);
        o.w = (uint)f2b(acc[6] * id) | ((uint)f2b(acc[7] * id) << 16);
        *(uint4*)(outb + (size_t)n * D + cg * 8) = o;
    }
}

// ---------------- layer-1 GEMM via MFMA (bf16 in, bf16 out) ----------------

__global__ __launch_bounds__(256, 2) void k_mm1m(
    const ushort* __restrict__ hb, const ushort* __restrict__ nbb,
    const ushort* __restrict__ wT, const float* __restrict__ b,
    ushort* __restrict__ x1b, int N) {
    __shared__ __align__(16) ushort As[128 * LDA];
    __shared__ __align__(16) ushort Bs[128 * LDA];
    int t    = threadIdx.x;
    int w    = t >> 6;
    int lane = t & 63;
    int m    = lane & 15;
    int quad = lane >> 4;
    int n0   = blockIdx.x * 128;

    f32x4 acc[2][8];
#pragma unroll
    for (int rt = 0; rt < 2; rt++)
#pragma unroll
        for (int ct = 0; ct < 8; ct++) acc[rt][ct] = (f32x4){0.f, 0.f, 0.f, 0.f};

#pragma unroll 1
    for (int kc = 0; kc < 8; kc++) {
        int k0 = kc * 32;
        const ushort* __restrict__ A = (k0 < 128) ? hb : nbb;
        int ka = k0 & 127;
        __syncthreads();
#pragma unroll
        for (int i = 0; i < 2; i++) {
            int linear = i * 256 + t;       // 0..511
            int row = linear >> 2;
            int q   = linear & 3;
            int nn = n0 + row;
            uint4 v = make_uint4(0u, 0u, 0u, 0u);
            if (nn < N) v = *(const uint4*)(A + (size_t)nn * D + ka + q * 8);
            *(uint4*)(&As[row * LDA + q * 8]) = v;
        }
#pragma unroll
        for (int i = 0; i < 2; i++) {
            int linear = i * 256 + t;
            int col = linear >> 2;
            int q   = linear & 3;
            uint4 v = *(const uint4*)(wT + (size_t)col * 256 + k0 + q * 8);
            *(uint4*)(&Bs[col * LDA + q * 8]) = v;
        }
        __syncthreads();
        short8 af[2], bf[8];
#pragma unroll
        for (int rt = 0; rt < 2; rt++)
            af[rt] = *(const short8*)(&As[(w * 32 + rt * 16 + m) * LDA + quad * 8]);
#pragma unroll
        for (int ct = 0; ct < 8; ct++)
            bf[ct] = *(const short8*)(&Bs[(ct * 16 + m) * LDA + quad * 8]);
#pragma unroll
        for (int rt = 0; rt < 2; rt++)
#pragma unroll
            for (int ct = 0; ct < 8; ct++)
                acc[rt][ct] = __builtin_amdgcn_mfma_f32_16x16x32_bf16(
                    af[rt], bf[ct], acc[rt][ct], 0, 0, 0);
    }
#pragma unroll
    for (int ct = 0; ct < 8; ct++) {
        float bias = b[ct * 16 + m];
#pragma unroll
        for (int rt = 0; rt < 2; rt++) {
#pragma unroll
            for (int r = 0; r < 4; r++) {
                int n = n0 + w * 32 + rt * 16 + quad * 4 + r;
                if (n < N)
                    x1b[(size_t)n * D + ct * 16 + m] =
                        f2b(fmaxf(acc[rt][ct][r] + bias, 0.f));
            }
        }
    }
}

// dense contraction S2_partial[chunk] = sum_{n in chunk} W[n,:]^T x1[n,:]
__global__ __launch_bounds__(256) void k_s2(
    const float* __restrict__ wc, const ushort* __restrict__ x1b,
    float* __restrict__ P, int N) {
    __shared__ float wl[4][64];
    __shared__ uint  xl[4][64];
    const uint* __restrict__ x1u = (const uint*)x1b;
    int t  = threadIdx.x;
    int gq = t >> 6;          // wave id = g-block, also node-load index
    int cp = t & 63;          // col pair -> cols 2*cp, 2*cp+1
    int chunk = blockIdx.x;
    int a = (int)(((long long)chunk * N) / NCH);
    int b = (int)(((long long)(chunk + 1) * N) / NCH);

    float acc[16][2];
#pragma unroll
    for (int g = 0; g < 16; g++) { acc[g][0] = 0.f; acc[g][1] = 0.f; }

    for (int n0 = a; n0 < b; n0 += 4) {
        int n = n0 + gq;
        bool ok = n < b;
        wl[gq][cp] = ok ? wc[(size_t)n * 64 + cp] : 0.f;
        xl[gq][cp] = ok ? x1u[(size_t)n * 64 + cp] : 0u;
        __syncthreads();
#pragma unroll
        for (int nn = 0; nn < 4; nn++) {
            uint xv = xl[nn][cp];
            float x0 = __uint_as_float(xv << 16);
            float x1 = __uint_as_float(xv & 0xffff0000u);
#pragma unroll
            for (int gg = 0; gg < 16; gg++) {
                float wv = wl[nn][gq * 16 + gg];
                acc[gg][0] = fmaf(wv, x0, acc[gg][0]);
                acc[gg][1] = fmaf(wv, x1, acc[gg][1]);
            }
        }
        __syncthreads();
    }
    float2* __restrict__ Pp = (float2*)(P + (size_t)chunk * 8192);
#pragma unroll
    for (int gg = 0; gg < 16; gg++)
        Pp[(gq * 16 + gg) * 64 + cp] = make_float2(acc[gg][0], acc[gg][1]);
}

// reduce partials: S2[i] += sum_ch P[ch][i]; grid (32, 8), S2 pre-zeroed
__global__ __launch_bounds__(256) void k_s2red(
    const float* __restrict__ P, float* __restrict__ S2) {
    int i = blockIdx.x * 256 + threadIdx.x;     // 0..8191
    int c0 = blockIdx.y * (NCH / 8);
    float s = 0.f;
#pragma unroll 8
    for (int ch = 0; ch < NCH / 8; ch++)
        s += P[(size_t)(c0 + ch) * 8192 + i];
    atomicAdd(&S2[i], s);
}

// ---------------- per-graph x1 sums (contiguous ranges via gstart) ----------

__global__ __launch_bounds__(256) void k_gsum1(
    const ushort* __restrict__ x1b, const int* __restrict__ gstart,
    float* __restrict__ S1) {
    int g  = blockIdx.x >> 3;
    int ch = blockIdx.x & 7;
    int r0 = gstart[g], r1 = gstart[g + 1];
    int len = r1 - r0;
    if (len <= 0) return;
    int L = (len + 7) >> 3;
    int a = r0 + ch * L;
    int bnd = min(a + L, r1);
    if (a >= bnd) return;

    int rp = threadIdx.x >> 6;    // 0..3 row phase
    int cp = threadIdx.x & 63;    // col pair
    float ax = 0.f, ay = 0.f;
    const uint* __restrict__ M = (const uint*)x1b;
    for (int n = a + rp; n < bnd; n += 4) {
        uint v = M[(size_t)n * 64 + cp];
        ax += __uint_as_float(v << 16);
        ay += __uint_as_float(v & 0xffff0000u);
    }
    atomicAdd(&S1[g * D + cp * 2], ax);
    atomicAdd(&S1[g * D + cp * 2 + 1], ay);
}

// ---------------- final: hg = (S1@W2s + S2@W2n)/cnt + b2 ; out = hg@Wc + bc ----

__global__ void k_final(const float* __restrict__ S1, const float* __restrict__ S2,
                        const int* __restrict__ gstart, const float* __restrict__ W2s,
                        const float* __restrict__ W2n, const float* __restrict__ b2,
                        const float* __restrict__ Wc, const float* __restrict__ bc,
                        float* __restrict__ out) {
    __shared__ float s1[D], s2[D], hg[D];
    int g = blockIdx.x, c = threadIdx.x;
    s1[c] = S1[g * D + c];
    s2[c] = S2[g * D + c];
    __syncthreads();
    float acc = 0.f;
#pragma unroll 8
    for (int k = 0; k < D; k++) {
        acc = fmaf(s1[k], W2s[k * D + c], acc);
        acc = fmaf(s2[k], W2n[k * D + c], acc);
    }
    int cnt = gstart[g + 1] - gstart[g];
    hg[c] = (cnt > 0) ? (acc / (float)cnt + b2[c]) : 0.f;
    __syncthreads();
    if (c < N_CLS) {
        float o = bc[c];
        for (int k = 0; k < D; k++) o = fmaf(hg[k], Wc[k * N_CLS + c], o);
        out[g * N_CLS + c] = o;
    }
}

// ---------------- launch ----------------

extern "C" void kernel_launch(void* const* d_in, const int* in_sizes, int n_in,
                              void* d_out, int out_size, void* d_ws, size_t ws_size,
                              hipStream_t stream) {
    const float* h   = (const float*)d_in[0];
    const int*   src = (const int*)d_in[1];
    const int*   dst = (const int*)d_in[2];
    const int*   gid = (const int*)d_in[3];
    const float* W1s = (const float*)d_in[5];
    const float* W1n = (const float*)d_in[6];
    const float* b1  = (const float*)d_in[7];
    const float* W2s = (const float*)d_in[8];
    const float* W2n = (const float*)d_in[9];
    const float* b2  = (const float*)d_in[10];
    const float* Wc  = (const float*)d_in[11];
    const float* bc  = (const float*)d_in[12];
    float* out = (float*)d_out;

    const int N = in_sizes[0] / D;  // 100000
    const int E = in_sizes[1];      // 1600000
    const int NB = (N + 255) >> 8;  // 391 buckets

    char* w = (char*)d_ws;
    size_t off = 0;
    auto alloc = [&](size_t elems) -> void* {   // elems are 4-byte units
        void* p = w + off;
        off += elems * 4;
        return p;
    };
    // zero-initialized region first (one memset)
    float* S1      = (float*)alloc((size_t)N_GRAPHS * D);
    float* S2      = (float*)alloc((size_t)N_GRAPHS * D);
    int*   bcount  = (int*)alloc(512);
    int*   bcount2 = (int*)alloc(512);
    size_t zero_bytes = off;
    int*   deg    = (int*)alloc(N);
    float* invdeg = (float*)alloc(N);
    int*   gstart = (int*)alloc(128);
    int*   csrf   = (int*)alloc((size_t)N * SLOTS);   // 19.2 MB padded CSR
    ushort* fb    = (ushort*)alloc((size_t)N * 64);   // bf16 [N,128] h
    ushort* nbb   = (ushort*)alloc((size_t)N * 64);   // bf16 [N,128] neigh1
    ushort* x1b   = (ushort*)alloc((size_t)N * 64);   // bf16 [N,128] x1
    ushort* wT    = (ushort*)alloc(16384);            // bf16 [128 cols][256 k]
    // aliases (dead-buffer reuse, no workspace growth):
    uint*  ebuf  = (uint*)nbb;   // dst-buckets: dead once k_aggb writes nbb
    uint*  ebuf2 = (uint*)csrf;  // src-buckets: csrf dead after (single) k_aggb
    float* wcoef = (float*)fb;   // [N,64] f32 coeffs: fb dead after k_mm1m
    float* P     = (float*)nbb;  // [NCH,64,128] f32 partials: nbb dead after k_mm1m
    (void)ws_size;

    hipMemsetAsync(d_ws, 0, zero_bytes, stream);

    int t4  = N * 32;  // float4 count of [N,128] f32

    k_cast<<<(t4 + 255) / 256, 256, 0, stream>>>(h, fb, t4);
    k_castw<<<128, 256, 0, stream>>>(W1s, W1n, wT);
    k_part<<<256, 256, 0, stream>>>(src, dst, bcount, ebuf, E, NB);
    k_bucket<<<NB, 1024, 0, stream>>>(ebuf, bcount, csrf, deg, invdeg, N);
    k_gbound<<<1, 128, 0, stream>>>(gid, gstart, N);
    k_aggb<<<(N + 3) / 4, 256, 0, stream>>>(fb, deg, csrf, invdeg, nbb, N);
    // csrf now dead -> src-side partition into its space
    k_part2<<<256, 256, 0, stream>>>(src, dst, bcount2, ebuf2, E, NB);
    k_mm1m<<<(N + 127) / 128, 256, 0, stream>>>(fb, nbb, wT, b1, x1b, N);
    // fb/nbb now dead: build layer-2 coefficient matrix + dense contraction
    k_wbucket<<<NB, 1024, 0, stream>>>(ebuf2, bcount2, gid, invdeg, wcoef, N);
    k_s2<<<NCH, 256, 0, stream>>>(wcoef, x1b, P, N);
    k_s2red<<<dim3(32, 8), 256, 0, stream>>>(P, S2);
    k_gsum1<<<N_GRAPHS * 8, 256, 0, stream>>>(x1b, gstart, S1);
    k_final<<<N_GRAPHS, 128, 0, stream>>>(S1, S2, gstart, W2s, W2n, b2, Wc, bc, out);
}

// Round 3
// 357.720 us; speedup vs baseline: 1.1504x; 1.0507x over previous
//
#include <hip/hip_runtime.h>

#define D        128
#define N_GRAPHS 64
#define N_CLS    16
#define LDA      40   // mm1m LDS row stride in bf16 (80 B: 16B-aligned, 2-way banks = free)
#define SLOTS    48   // padded CSR width; deg ~ Poisson(16), P(>48) ~ 1e-11
#define CAP      8192 // bucket capacity (avg 4096, std ~64 -> 2x margin)

typedef unsigned int   uint;
typedef unsigned short ushort;
typedef __attribute__((ext_vector_type(8))) short short8;
typedef __attribute__((ext_vector_type(4))) float f32x4;

__device__ inline ushort f2b(float f) {   // f32 -> bf16 RNE
    uint u = __float_as_uint(f);
    u += 0x7fffu + ((u >> 16) & 1u);
    return (ushort)(u >> 16);
}

// swizzled u16 index into a [row][256] LDS tile: XOR 8-u16 groups by (row>>3)&7.
// Keeps 8-u16 (16B) groups intact -> b128 reads stay aligned; spreads banks.
__device__ __forceinline__ int swzi(int row, int col) {
    return row * 256 + (col ^ (((row >> 3) & 7) << 3));
}

// ===================== dispatch 1: boot (part | castw | gbound | cast) ======
// Independent setup work fused into one launch via block ranges.

__global__ __launch_bounds__(256) void k_boot(
    const float* __restrict__ h, ushort* __restrict__ fb,
    const float* __restrict__ Ws, const float* __restrict__ Wn,
    ushort* __restrict__ wT,
    const int* __restrict__ gid, int* __restrict__ gstart,
    const int* __restrict__ src, const int* __restrict__ dst,
    int* __restrict__ bcount, uint* __restrict__ ebuf,
    int E, int NB, int N, int t4) {
    __shared__ int hist[512], base[512], lcur[512];
    int bb = blockIdx.x;
    int t  = threadIdx.x;

    if (bb < 256) {
        // ---- phase A: partition edges into 256-node buckets by dst ----
        int per = (E + 255) / 256;
        int e0 = bb * per;
        int e1 = min(e0 + per, E);
        for (int i = t; i < NB; i += 256) { hist[i] = 0; lcur[i] = 0; }
        __syncthreads();
        for (int e = e0 + t; e < e1; e += 256) atomicAdd(&hist[dst[e] >> 8], 1);
        __syncthreads();
        for (int i = t; i < NB; i += 256)
            base[i] = hist[i] ? atomicAdd(&bcount[i], hist[i]) : 0;
        __syncthreads();
        for (int e = e0 + t; e < e1; e += 256) {
            int dd = dst[e];
            int b = dd >> 8;
            int off = atomicAdd(&lcur[b], 1);
            int pos = base[b] + off;
            if (pos < CAP)
                ebuf[(size_t)b * CAP + pos] = ((uint)src[e] << 8) | (uint)(dd & 255);
        }
    } else if (bb < 384) {
        // ---- castw: wT[col][k] (k=0..255: Ws rows then Wn rows), bf16 ----
        int i = (bb - 256) * 256 + t;   // 0..32767
        int c = i >> 8, k = i & 255;
        float v = (k < 128) ? Ws[k * 128 + c] : Wn[(k - 128) * 128 + c];
        wT[c * 256 + k] = f2b(v);
    } else if (bb == 384) {
        // ---- gbound: gstart[g] = lower_bound(gid, g) ----
        int g = t;
        if (g <= N_GRAPHS) {
            int lo = 0, hi = N;
            while (lo < hi) {
                int mid = (lo + hi) >> 1;
                if (gid[mid] < g) lo = mid + 1; else hi = mid;
            }
            gstart[g] = lo;
        }
    } else {
        // ---- cast h (f32) -> fb (bf16) ----
        int i = (bb - 385) * 256 + t;
        if (i < t4) {
            float4 v = ((const float4*)h)[i];
            ushort4 o;
            o.x = f2b(v.x); o.y = f2b(v.y); o.z = f2b(v.z); o.w = f2b(v.w);
            ((ushort4*)fb)[i] = o;
        }
    }
}

// ===================== dispatch 2: per-bucket CSR build =====================

__global__ __launch_bounds__(1024) void k_bucket(
    const uint* __restrict__ ebuf, const int* __restrict__ bcount,
    int* __restrict__ csrf, int* __restrict__ deg, float* __restrict__ invdeg,
    int N) {
    __shared__ int ldeg[256];
    __shared__ int lcsr[256 * SLOTS];
    int b = blockIdx.x, t = threadIdx.x;
    if (t < 256) ldeg[t] = 0;
    __syncthreads();
    int cnt = bcount[b];
    if (cnt > CAP) cnt = CAP;
    const uint* __restrict__ eb = ebuf + (size_t)b * CAP;
    for (int i = t; i < cnt; i += 1024) {
        uint r = eb[i];
        int dl = r & 255;
        int sl = atomicAdd(&ldeg[dl], 1);
        if (sl < SLOTS) lcsr[dl * SLOTS + sl] = (int)(r >> 8);
    }
    __syncthreads();
    int n0 = b << 8;
    int lim = (N - n0) * SLOTS;
    if (lim > 256 * SLOTS) lim = 256 * SLOTS;
    for (int i = t; i < lim; i += 1024)
        csrf[(size_t)n0 * SLOTS + i] = lcsr[i];
    if (t < 256 && n0 + t < N) {
        int d = ldeg[t];
        deg[n0 + t] = d;
        invdeg[n0 + t] = 1.0f / (float)(d > 1 ? d : 1);
    }
}

// ===================== dispatch 3: bf16 neighbor-mean gather ================

__global__ __launch_bounds__(256) void k_aggb(
    const ushort* __restrict__ fb, const int* __restrict__ deg,
    const int* __restrict__ csrf, const float* __restrict__ invdeg,
    ushort* __restrict__ outb, int N) {
    int lane = threadIdx.x & 63;
    int n = blockIdx.x * 4 + (threadIdx.x >> 6);
    if (n >= N) return;
    int d = deg[n];
    if (d > SLOTS) d = SLOTS;
    const int* __restrict__ lst = csrf + (size_t)n * SLOTS;
    int ej = lane >> 4;      // 0..3
    int cg = lane & 15;      // cols cg*8 .. cg*8+7

    float acc[8];
#pragma unroll
    for (int i = 0; i < 8; i++) acc[i] = 0.f;

    int e = ej;
    for (; e + 4 < d; e += 8) {
        int s0 = lst[e];
        int s1 = lst[e + 4];
        uint4 v0 = *(const uint4*)(fb + (size_t)s0 * D + cg * 8);
        uint4 v1 = *(const uint4*)(fb + (size_t)s1 * D + cg * 8);
        acc[0] += __uint_as_float(v0.x << 16);
        acc[1] += __uint_as_float(v0.x & 0xffff0000u);
        acc[2] += __uint_as_float(v0.y << 16);
        acc[3] += __uint_as_float(v0.y & 0xffff0000u);
        acc[4] += __uint_as_float(v0.z << 16);
        acc[5] += __uint_as_float(v0.z & 0xffff0000u);
        acc[6] += __uint_as_float(v0.w << 16);
        acc[7] += __uint_as_float(v0.w & 0xffff0000u);
        acc[0] += __uint_as_float(v1.x << 16);
        acc[1] += __uint_as_float(v1.x & 0xffff0000u);
        acc[2] += __uint_as_float(v1.y << 16);
        acc[3] += __uint_as_float(v1.y & 0xffff0000u);
        acc[4] += __uint_as_float(v1.z << 16);
        acc[5] += __uint_as_float(v1.z & 0xffff0000u);
        acc[6] += __uint_as_float(v1.w << 16);
        acc[7] += __uint_as_float(v1.w & 0xffff0000u);
    }
    for (; e < d; e += 4) {
        int s = lst[e];
        uint4 v = *(const uint4*)(fb + (size_t)s * D + cg * 8);
        acc[0] += __uint_as_float(v.x << 16);
        acc[1] += __uint_as_float(v.x & 0xffff0000u);
        acc[2] += __uint_as_float(v.y << 16);
        acc[3] += __uint_as_float(v.y & 0xffff0000u);
        acc[4] += __uint_as_float(v.z << 16);
        acc[5] += __uint_as_float(v.z & 0xffff0000u);
        acc[6] += __uint_as_float(v.w << 16);
        acc[7] += __uint_as_float(v.w & 0xffff0000u);
    }
#pragma unroll
    for (int i = 0; i < 8; i++) {
        acc[i] += __shfl_xor(acc[i], 16);
        acc[i] += __shfl_xor(acc[i], 32);
    }
    if (ej == 0) {
        float id = invdeg[n];
        uint4 o;
        o.x = (uint)f2b(acc[0] * id) | ((uint)f2b(acc[1] * id) << 16);
        o.y = (uint)f2b(acc[2] * id) | ((uint)f2b(acc[3] * id) << 16);
        o.z = (uint)f2b(acc[4] * id) | ((uint)f2b(acc[5] * id) << 16);
        o.w = (uint)f2b(acc[6] * id) | ((uint)f2b(acc[7] * id) << 16);
        *(uint4*)(outb + (size_t)n * D + cg * 8) = o;
    }
}

// ===================== dispatch 4: mm1m | part2 =============================
// mm1m: layer-1 GEMM (MFMA, bf16). part2: src-bucket edge partition with
// precomputed (src-lane | gid[dst] | degcode[dst]) records -> k_ws2 needs no
// random lookups. csrf is dead after k_aggb, so ebuf2 reuses its space.

__global__ __launch_bounds__(256, 2) void k_mmp2(
    const ushort* __restrict__ hb, const ushort* __restrict__ nbb,
    const ushort* __restrict__ wT, const float* __restrict__ b,
    ushort* __restrict__ x1b, int N, int MMB,
    const int* __restrict__ src, const int* __restrict__ dst,
    const int* __restrict__ gid, const int* __restrict__ deg,
    int* __restrict__ bcount2, uint* __restrict__ ebuf2, int E, int NB) {
    __shared__ __align__(16) ushort As[128 * LDA];
    __shared__ __align__(16) ushort Bs[128 * LDA];
    __shared__ int hist[512], base[512], lcur[512];

    if (blockIdx.x >= MMB) {
        // ---------------- part2 ----------------
        int bb = blockIdx.x - MMB;   // 0..255
        int t = threadIdx.x;
        int per = (E + 255) / 256;
        int e0 = bb * per;
        int e1 = min(e0 + per, E);
        for (int i = t; i < NB; i += 256) { hist[i] = 0; lcur[i] = 0; }
        __syncthreads();
        for (int e = e0 + t; e < e1; e += 256) atomicAdd(&hist[src[e] >> 8], 1);
        __syncthreads();
        for (int i = t; i < NB; i += 256)
            base[i] = hist[i] ? atomicAdd(&bcount2[i], hist[i]) : 0;
        __syncthreads();
        for (int e = e0 + t; e < e1; e += 256) {
            int ss = src[e];
            int dd = dst[e];
            int bk = ss >> 8;
            int off = atomicAdd(&lcur[bk], 1);
            int pos = base[bk] + off;
            if (pos < CAP) {
                int g  = gid[dd];                 // 0..63
                int dc = deg[dd]; if (dc > 127) dc = 127;
                ebuf2[(size_t)bk * CAP + pos] =
                    (uint)(ss & 255) | ((uint)g << 8) | ((uint)dc << 14);
            }
        }
        return;
    }

    // ---------------- mm1m ----------------
    int t    = threadIdx.x;
    int w    = t >> 6;
    int lane = t & 63;
    int m    = lane & 15;
    int quad = lane >> 4;
    int n0   = blockIdx.x * 128;

    f32x4 acc[2][8];
#pragma unroll
    for (int rt = 0; rt < 2; rt++)
#pragma unroll
        for (int ct = 0; ct < 8; ct++) acc[rt][ct] = (f32x4){0.f, 0.f, 0.f, 0.f};

#pragma unroll 1
    for (int kc = 0; kc < 8; kc++) {
        int k0 = kc * 32;
        const ushort* __restrict__ A = (k0 < 128) ? hb : nbb;
        int ka = k0 & 127;
        __syncthreads();
#pragma unroll
        for (int i = 0; i < 2; i++) {
            int linear = i * 256 + t;       // 0..511
            int row = linear >> 2;
            int q   = linear & 3;
            int nn = n0 + row;
            uint4 v = make_uint4(0u, 0u, 0u, 0u);
            if (nn < N) v = *(const uint4*)(A + (size_t)nn * D + ka + q * 8);
            *(uint4*)(&As[row * LDA + q * 8]) = v;
        }
#pragma unroll
        for (int i = 0; i < 2; i++) {
            int linear = i * 256 + t;
            int col = linear >> 2;
            int q   = linear & 3;
            uint4 v = *(const uint4*)(wT + (size_t)col * 256 + k0 + q * 8);
            *(uint4*)(&Bs[col * LDA + q * 8]) = v;
        }
        __syncthreads();
        short8 af[2], bf[8];
#pragma unroll
        for (int rt = 0; rt < 2; rt++)
            af[rt] = *(const short8*)(&As[(w * 32 + rt * 16 + m) * LDA + quad * 8]);
#pragma unroll
        for (int ct = 0; ct < 8; ct++)
            bf[ct] = *(const short8*)(&Bs[(ct * 16 + m) * LDA + quad * 8]);
#pragma unroll
        for (int rt = 0; rt < 2; rt++)
#pragma unroll
            for (int ct = 0; ct < 8; ct++)
                acc[rt][ct] = __builtin_amdgcn_mfma_f32_16x16x32_bf16(
                    af[rt], bf[ct], acc[rt][ct], 0, 0, 0);
    }
#pragma unroll
    for (int ct = 0; ct < 8; ct++) {
        float bias = b[ct * 16 + m];
#pragma unroll
        for (int rt = 0; rt < 2; rt++) {
#pragma unroll
            for (int r = 0; r < 4; r++) {
                int n = n0 + w * 32 + rt * 16 + quad * 4 + r;
                if (n < N)
                    x1b[(size_t)n * D + ct * 16 + m] =
                        f2b(fmaxf(acc[rt][ct][r] + bias, 0.f));
            }
        }
    }
}

// ===================== dispatch 5: ws2 | gsum1 ==============================
// ws2 (blocks [0,NB)): per src-bucket, S2[g][d] += sum_n wc[g][n]*x1[n][d]:
//   1) build wcT[64][256] f32 in LDS from part2 records (LDS atomics)
//   2) split into bf16 hi+lo (error ~2^-16: exactness preserved)
//   3) transpose-stage x1 bucket slice into LDS (XOR-swizzled)
//   4) 128 MFMA/wave (K=256), atomicAdd the 64x128 tile into S2.
// gsum1 (blocks [NB, NB+512)): per-graph x1 sums (contiguous via gstart).

__global__ __launch_bounds__(256, 1) void k_wg(
    const uint* __restrict__ ebuf2, const int* __restrict__ bcount2,
    const ushort* __restrict__ x1b, const int* __restrict__ gstart,
    float* __restrict__ S1, float* __restrict__ S2, int N, int WSB) {
    __shared__ __align__(16) char smem[131072];   // 128 KiB

    if (blockIdx.x >= WSB) {
        // ---------------- gsum1 ----------------
        int b2 = blockIdx.x - WSB;
        int g  = b2 >> 3;
        int ch = b2 & 7;
        int r0 = gstart[g], r1 = gstart[g + 1];
        int len = r1 - r0;
        if (len <= 0) return;
        int L = (len + 7) >> 3;
        int a = r0 + ch * L;
        int bnd = min(a + L, r1);
        if (a >= bnd) return;
        int rp = threadIdx.x >> 6;
        int cp = threadIdx.x & 63;
        float ax = 0.f, ay = 0.f;
        const uint* __restrict__ M = (const uint*)x1b;
        for (int n = a + rp; n < bnd; n += 4) {
            uint v = M[(size_t)n * 64 + cp];
            ax += __uint_as_float(v << 16);
            ay += __uint_as_float(v & 0xffff0000u);
        }
        atomicAdd(&S1[g * D + cp * 2], ax);
        atomicAdd(&S1[g * D + cp * 2 + 1], ay);
        return;
    }

    // ---------------- ws2 ----------------
    float*  lwcT = (float*)smem;             // [64][256] f32 (build phase)
    ushort* lxT  = (ushort*)smem;            // [128][256] u16 swz (overwrites lwcT)
    ushort* lwcb = (ushort*)(smem + 65536);  // [64][256] u16 swz (hi)
    ushort* lwlo = (ushort*)(smem + 98304);  // [64][256] u16 swz (lo)

    int b = blockIdx.x, t = threadIdx.x;
    int n0 = b << 8;

    for (int i = t; i < 16384; i += 256) lwcT[i] = 0.f;
    __syncthreads();

    int cnt = bcount2[b];
    if (cnt > CAP) cnt = CAP;
    const uint* __restrict__ eb = ebuf2 + (size_t)b * CAP;
    for (int i = t; i < cnt; i += 256) {
        uint r = eb[i];
        int sl = (int)(r & 255u);
        int g  = (int)((r >> 8) & 63u);
        int dc = (int)((r >> 14) & 127u);
        float id = 1.0f / (float)(dc > 1 ? dc : 1);   // == invdeg[dst] exactly
        atomicAdd(&lwcT[g * 256 + sl], id);
    }
    __syncthreads();

    for (int i = t; i < 16384; i += 256) {
        int g = i >> 8, sl = i & 255;
        float v = lwcT[i];
        ushort hi = f2b(v);
        float fhi = __uint_as_float((uint)hi << 16);
        ushort lo = f2b(v - fhi);
        int si = swzi(g, sl);
        lwcb[si] = hi;
        lwlo[si] = lo;
    }
    __syncthreads();   // lwcT fully consumed -> safe to overwrite with lxT

    const uint4* __restrict__ x4 = (const uint4*)x1b;
#pragma unroll 1
    for (int it = 0; it < 16; ++it) {
        int l = it * 256 + t;
        int n = l >> 4, q = l & 15;
        uint4 v = make_uint4(0u, 0u, 0u, 0u);
        int nn = n0 + n;
        if (nn < N) v = x4[(size_t)nn * 16 + q];
        int d0 = q * 8;
        lxT[swzi(d0 + 0, n)] = (ushort)(v.x & 0xffffu);
        lxT[swzi(d0 + 1, n)] = (ushort)(v.x >> 16);
        lxT[swzi(d0 + 2, n)] = (ushort)(v.y & 0xffffu);
        lxT[swzi(d0 + 3, n)] = (ushort)(v.y >> 16);
        lxT[swzi(d0 + 4, n)] = (ushort)(v.z & 0xffffu);
        lxT[swzi(d0 + 5, n)] = (ushort)(v.z >> 16);
        lxT[swzi(d0 + 6, n)] = (ushort)(v.w & 0xffffu);
        lxT[swzi(d0 + 7, n)] = (ushort)(v.w >> 16);
    }
    __syncthreads();

    int wv = t >> 6, lane = t & 63, m = lane & 15, quad = lane >> 4;
    f32x4 acc[8];
#pragma unroll
    for (int dt = 0; dt < 8; ++dt) acc[dt] = (f32x4){0.f, 0.f, 0.f, 0.f};

#pragma unroll 1
    for (int k8 = 0; k8 < 8; ++k8) {
        int kc = k8 * 32 + quad * 8;
        int ar = wv * 16 + m;
        short8 ahi = *(const short8*)&lwcb[swzi(ar, kc)];
        short8 alo = *(const short8*)&lwlo[swzi(ar, kc)];
#pragma unroll
        for (int dt = 0; dt < 8; ++dt) {
            short8 bfr = *(const short8*)&lxT[swzi(dt * 16 + m, kc)];
            acc[dt] = __builtin_amdgcn_mfma_f32_16x16x32_bf16(alo, bfr, acc[dt], 0, 0, 0);
            acc[dt] = __builtin_amdgcn_mfma_f32_16x16x32_bf16(ahi, bfr, acc[dt], 0, 0, 0);
        }
    }
#pragma unroll
    for (int dt = 0; dt < 8; ++dt) {
#pragma unroll
        for (int r = 0; r < 4; ++r) {
            int g = wv * 16 + quad * 4 + r;
            atomicAdd(&S2[g * 128 + dt * 16 + m], acc[dt][r]);
        }
    }
}

// ===================== dispatch 6: final ====================================

__global__ void k_final(const float* __restrict__ S1, const float* __restrict__ S2,
                        const int* __restrict__ gstart, const float* __restrict__ W2s,
                        const float* __restrict__ W2n, const float* __restrict__ b2,
                        const float* __restrict__ Wc, const float* __restrict__ bc,
                        float* __restrict__ out) {
    __shared__ float s1[D], s2[D], hg[D];
    int g = blockIdx.x, c = threadIdx.x;
    s1[c] = S1[g * D + c];
    s2[c] = S2[g * D + c];
    __syncthreads();
    float acc = 0.f;
#pragma unroll 8
    for (int k = 0; k < D; k++) {
        acc = fmaf(s1[k], W2s[k * D + c], acc);
        acc = fmaf(s2[k], W2n[k * D + c], acc);
    }
    int cnt = gstart[g + 1] - gstart[g];
    hg[c] = (cnt > 0) ? (acc / (float)cnt + b2[c]) : 0.f;
    __syncthreads();
    if (c < N_CLS) {
        float o = bc[c];
        for (int k = 0; k < D; k++) o = fmaf(hg[k], Wc[k * N_CLS + c], o);
        out[g * N_CLS + c] = o;
    }
}

// ===================== launch ===============================================

extern "C" void kernel_launch(void* const* d_in, const int* in_sizes, int n_in,
                              void* d_out, int out_size, void* d_ws, size_t ws_size,
                              hipStream_t stream) {
    const float* h   = (const float*)d_in[0];
    const int*   src = (const int*)d_in[1];
    const int*   dst = (const int*)d_in[2];
    const int*   gid = (const int*)d_in[3];
    const float* W1s = (const float*)d_in[5];
    const float* W1n = (const float*)d_in[6];
    const float* b1  = (const float*)d_in[7];
    const float* W2s = (const float*)d_in[8];
    const float* W2n = (const float*)d_in[9];
    const float* b2  = (const float*)d_in[10];
    const float* Wc  = (const float*)d_in[11];
    const float* bc  = (const float*)d_in[12];
    float* out = (float*)d_out;

    const int N = in_sizes[0] / D;  // 100000
    const int E = in_sizes[1];      // 1600000
    const int NB = (N + 255) >> 8;  // 391 buckets

    char* w = (char*)d_ws;
    size_t off = 0;
    auto alloc = [&](size_t elems) -> void* {   // elems are 4-byte units
        void* p = w + off;
        off += elems * 4;
        return p;
    };
    // zero-initialized region first (one memset)
    float* S1      = (float*)alloc((size_t)N_GRAPHS * D);
    float* S2      = (float*)alloc((size_t)N_GRAPHS * D);
    int*   bcount  = (int*)alloc(512);
    int*   bcount2 = (int*)alloc(512);
    size_t zero_bytes = off;
    int*   deg    = (int*)alloc(N);
    float* invdeg = (float*)alloc(N);
    int*   gstart = (int*)alloc(128);
    int*   csrf   = (int*)alloc((size_t)N * SLOTS);   // 19.2 MB padded CSR
    ushort* fb    = (ushort*)alloc((size_t)N * 64);   // bf16 [N,128] h
    ushort* nbb   = (ushort*)alloc((size_t)N * 64);   // bf16 [N,128] neigh1
    ushort* x1b   = (ushort*)alloc((size_t)N * 64);   // bf16 [N,128] x1
    ushort* wT    = (ushort*)alloc(16384);            // bf16 [128 cols][256 k]
    // aliases (dead-buffer reuse, no workspace growth):
    uint*  ebuf  = (uint*)nbb;   // dst-buckets: dead once k_aggb writes nbb
    uint*  ebuf2 = (uint*)csrf;  // src-buckets: csrf dead after k_aggb
    (void)ws_size;

    hipMemsetAsync(d_ws, 0, zero_bytes, stream);

    int t4 = N * 32;                   // float4 count of [N,128] f32
    int CB = (t4 + 255) / 256;         // cast blocks
    int MMB = (N + 127) / 128;         // mm1m blocks

    // 1: part | castw | gbound | cast
    k_boot<<<256 + 128 + 1 + CB, 256, 0, stream>>>(
        h, fb, W1s, W1n, wT, gid, gstart, src, dst, bcount, ebuf, E, NB, N, t4);
    // 2: CSR build
    k_bucket<<<NB, 1024, 0, stream>>>(ebuf, bcount, csrf, deg, invdeg, N);
    // 3: neighbor-mean gather (layer 1)
    k_aggb<<<(N + 3) / 4, 256, 0, stream>>>(fb, deg, csrf, invdeg, nbb, N);
    // 4: mm1m | part2 (csrf dead -> ebuf2 in its space)
    k_mmp2<<<MMB + 256, 256, 0, stream>>>(
        fb, nbb, wT, b1, x1b, N, MMB, src, dst, gid, deg, bcount2, ebuf2, E, NB);
    // 5: ws2 (MFMA collapse of layer-2 agg + graph mean) | gsum1
    k_wg<<<NB + N_GRAPHS * 8, 256, 0, stream>>>(
        ebuf2, bcount2, x1b, gstart, S1, S2, N, NB);
    // 6: final
    k_final<<<N_GRAPHS, 128, 0, stream>>>(S1, S2, gstart, W2s, W2n, b2, Wc, bc, out);
}

// Round 4
// 334.367 us; speedup vs baseline: 1.2308x; 1.0698x over previous
//
#include <hip/hip_runtime.h>

#define D        128
#define N_GRAPHS 64
#define N_CLS    16
#define LDA      40   // mm1m LDS row stride in bf16 (80 B: 16B-aligned, 2-way banks = free)
#define SLOTS    48   // padded CSR width; deg ~ Poisson(16), P(>48) ~ 1e-11
#define CAP      8192 // bucket capacity (avg 4096, std ~64 -> 2x margin)

typedef unsigned int   uint;
typedef unsigned short ushort;
typedef __attribute__((ext_vector_type(8))) short short8;
typedef __attribute__((ext_vector_type(4))) float f32x4;

__device__ inline ushort f2b(float f) {   // f32 -> bf16 RNE
    uint u = __float_as_uint(f);
    u += 0x7fffu + ((u >> 16) & 1u);
    return (ushort)(u >> 16);
}

// swizzled u16 index into a [row][256] LDS tile.
// XOR by ((row ^ (row>>3)) & 7) << 3: keeps 8-u16 (16 B) groups intact for
// b128 reads; varies with BOTH row&7 (spreads the MFMA-read lanes, which
// differ in low row bits) and row>>3 (spreads the transpose-staging writes,
// which differ only in bits 3..6 of row). Both patterns end up <=2-way.
__device__ __forceinline__ int swz2i(int row, int col) {
    return row * 256 + (col ^ (((row ^ (row >> 3)) & 7) << 3));
}

// ===================== dispatch 1: boot (part | castw | gbound | cast) ======

__global__ __launch_bounds__(256) void k_boot(
    const float* __restrict__ h, ushort* __restrict__ fb,
    const float* __restrict__ Ws, const float* __restrict__ Wn,
    ushort* __restrict__ wT,
    const int* __restrict__ gid, int* __restrict__ gstart,
    const int* __restrict__ src, const int* __restrict__ dst,
    int* __restrict__ bcount, uint* __restrict__ ebuf,
    int E, int NB, int N, int t4) {
    __shared__ int hist[512], base[512], lcur[512];
    int bb = blockIdx.x;
    int t  = threadIdx.x;

    if (bb < 256) {
        // ---- partition edges into 256-node buckets by dst ----
        int per = (E + 255) / 256;
        int e0 = bb * per;
        int e1 = min(e0 + per, E);
        for (int i = t; i < NB; i += 256) { hist[i] = 0; lcur[i] = 0; }
        __syncthreads();
        for (int e = e0 + t; e < e1; e += 256) atomicAdd(&hist[dst[e] >> 8], 1);
        __syncthreads();
        for (int i = t; i < NB; i += 256)
            base[i] = hist[i] ? atomicAdd(&bcount[i], hist[i]) : 0;
        __syncthreads();
        for (int e = e0 + t; e < e1; e += 256) {
            int dd = dst[e];
            int b = dd >> 8;
            int off = atomicAdd(&lcur[b], 1);
            int pos = base[b] + off;
            if (pos < CAP)
                ebuf[(size_t)b * CAP + pos] = ((uint)src[e] << 8) | (uint)(dd & 255);
        }
    } else if (bb < 384) {
        // ---- castw: wT[col][k] (k=0..255: Ws rows then Wn rows), bf16 ----
        int i = (bb - 256) * 256 + t;   // 0..32767
        int c = i >> 8, k = i & 255;
        float v = (k < 128) ? Ws[k * 128 + c] : Wn[(k - 128) * 128 + c];
        wT[c * 256 + k] = f2b(v);
    } else if (bb == 384) {
        // ---- gbound: gstart[g] = lower_bound(gid, g) ----
        int g = t;
        if (g <= N_GRAPHS) {
            int lo = 0, hi = N;
            while (lo < hi) {
                int mid = (lo + hi) >> 1;
                if (gid[mid] < g) lo = mid + 1; else hi = mid;
            }
            gstart[g] = lo;
        }
    } else {
        // ---- cast h (f32) -> fb (bf16) ----
        int i = (bb - 385) * 256 + t;
        if (i < t4) {
            float4 v = ((const float4*)h)[i];
            ushort4 o;
            o.x = f2b(v.x); o.y = f2b(v.y); o.z = f2b(v.z); o.w = f2b(v.w);
            ((ushort4*)fb)[i] = o;
        }
    }
}

// ===================== dispatch 2: per-bucket CSR build =====================

__global__ __launch_bounds__(1024) void k_bucket(
    const uint* __restrict__ ebuf, const int* __restrict__ bcount,
    int* __restrict__ csrf, int* __restrict__ deg, float* __restrict__ invdeg,
    int N) {
    __shared__ int ldeg[256];
    __shared__ int lcsr[256 * SLOTS];
    int b = blockIdx.x, t = threadIdx.x;
    if (t < 256) ldeg[t] = 0;
    __syncthreads();
    int cnt = bcount[b];
    if (cnt > CAP) cnt = CAP;
    const uint* __restrict__ eb = ebuf + (size_t)b * CAP;
    for (int i = t; i < cnt; i += 1024) {
        uint r = eb[i];
        int dl = r & 255;
        int sl = atomicAdd(&ldeg[dl], 1);
        if (sl < SLOTS) lcsr[dl * SLOTS + sl] = (int)(r >> 8);
    }
    __syncthreads();
    int n0 = b << 8;
    int lim = (N - n0) * SLOTS;
    if (lim > 256 * SLOTS) lim = 256 * SLOTS;
    for (int i = t; i < lim; i += 1024)
        csrf[(size_t)n0 * SLOTS + i] = lcsr[i];
    if (t < 256 && n0 + t < N) {
        int d = ldeg[t];
        deg[n0 + t] = d;
        invdeg[n0 + t] = 1.0f / (float)(d > 1 ? d : 1);
    }
}

// ===================== dispatch 3: bf16 neighbor-mean gather ================

__global__ __launch_bounds__(256) void k_aggb(
    const ushort* __restrict__ fb, const int* __restrict__ deg,
    const int* __restrict__ csrf, const float* __restrict__ invdeg,
    ushort* __restrict__ outb, int N) {
    int lane = threadIdx.x & 63;
    int n = blockIdx.x * 4 + (threadIdx.x >> 6);
    if (n >= N) return;
    int d = deg[n];
    if (d > SLOTS) d = SLOTS;
    const int* __restrict__ lst = csrf + (size_t)n * SLOTS;
    int ej = lane >> 4;      // 0..3
    int cg = lane & 15;      // cols cg*8 .. cg*8+7

    float acc[8];
#pragma unroll
    for (int i = 0; i < 8; i++) acc[i] = 0.f;

    int e = ej;
    for (; e + 4 < d; e += 8) {
        int s0 = lst[e];
        int s1 = lst[e + 4];
        uint4 v0 = *(const uint4*)(fb + (size_t)s0 * D + cg * 8);
        uint4 v1 = *(const uint4*)(fb + (size_t)s1 * D + cg * 8);
        acc[0] += __uint_as_float(v0.x << 16);
        acc[1] += __uint_as_float(v0.x & 0xffff0000u);
        acc[2] += __uint_as_float(v0.y << 16);
        acc[3] += __uint_as_float(v0.y & 0xffff0000u);
        acc[4] += __uint_as_float(v0.z << 16);
        acc[5] += __uint_as_float(v0.z & 0xffff0000u);
        acc[6] += __uint_as_float(v0.w << 16);
        acc[7] += __uint_as_float(v0.w & 0xffff0000u);
        acc[0] += __uint_as_float(v1.x << 16);
        acc[1] += __uint_as_float(v1.x & 0xffff0000u);
        acc[2] += __uint_as_float(v1.y << 16);
        acc[3] += __uint_as_float(v1.y & 0xffff0000u);
        acc[4] += __uint_as_float(v1.z << 16);
        acc[5] += __uint_as_float(v1.z & 0xffff0000u);
        acc[6] += __uint_as_float(v1.w << 16);
        acc[7] += __uint_as_float(v1.w & 0xffff0000u);
    }
    for (; e < d; e += 4) {
        int s = lst[e];
        uint4 v = *(const uint4*)(fb + (size_t)s * D + cg * 8);
        acc[0] += __uint_as_float(v.x << 16);
        acc[1] += __uint_as_float(v.x & 0xffff0000u);
        acc[2] += __uint_as_float(v.y << 16);
        acc[3] += __uint_as_float(v.y & 0xffff0000u);
        acc[4] += __uint_as_float(v.z << 16);
        acc[5] += __uint_as_float(v.z & 0xffff0000u);
        acc[6] += __uint_as_float(v.w << 16);
        acc[7] += __uint_as_float(v.w & 0xffff0000u);
    }
#pragma unroll
    for (int i = 0; i < 8; i++) {
        acc[i] += __shfl_xor(acc[i], 16);
        acc[i] += __shfl_xor(acc[i], 32);
    }
    if (ej == 0) {
        float id = invdeg[n];
        uint4 o;
        o.x = (uint)f2b(acc[0] * id) | ((uint)f2b(acc[1] * id) << 16);
        o.y = (uint)f2b(acc[2] * id) | ((uint)f2b(acc[3] * id) << 16);
        o.z = (uint)f2b(acc[4] * id) | ((uint)f2b(acc[5] * id) << 16);
        o.w = (uint)f2b(acc[6] * id) | ((uint)f2b(acc[7] * id) << 16);
        *(uint4*)(outb + (size_t)n * D + cg * 8) = o;
    }
}

// ===================== dispatch 4: mm1m | part2 =============================

__global__ __launch_bounds__(256, 2) void k_mmp2(
    const ushort* __restrict__ hb, const ushort* __restrict__ nbb,
    const ushort* __restrict__ wT, const float* __restrict__ b,
    ushort* __restrict__ x1b, int N, int MMB,
    const int* __restrict__ src, const int* __restrict__ dst,
    const int* __restrict__ gid, const int* __restrict__ deg,
    int* __restrict__ bcount2, uint* __restrict__ ebuf2, int E, int NB) {
    __shared__ __align__(16) ushort As[128 * LDA];
    __shared__ __align__(16) ushort Bs[128 * LDA];
    __shared__ int hist[512], base[512], lcur[512];

    if (blockIdx.x >= MMB) {
        // ---------------- part2: src-bucket partition ----------------
        int bb = blockIdx.x - MMB;   // 0..255
        int t = threadIdx.x;
        int per = (E + 255) / 256;
        int e0 = bb * per;
        int e1 = min(e0 + per, E);
        for (int i = t; i < NB; i += 256) { hist[i] = 0; lcur[i] = 0; }
        __syncthreads();
        for (int e = e0 + t; e < e1; e += 256) atomicAdd(&hist[src[e] >> 8], 1);
        __syncthreads();
        for (int i = t; i < NB; i += 256)
            base[i] = hist[i] ? atomicAdd(&bcount2[i], hist[i]) : 0;
        __syncthreads();
        for (int e = e0 + t; e < e1; e += 256) {
            int ss = src[e];
            int dd = dst[e];
            int bk = ss >> 8;
            int off = atomicAdd(&lcur[bk], 1);
            int pos = base[bk] + off;
            if (pos < CAP) {
                int g  = gid[dd];                 // 0..63
                int dc = deg[dd]; if (dc > 127) dc = 127;
                ebuf2[(size_t)bk * CAP + pos] =
                    (uint)(ss & 255) | ((uint)g << 8) | ((uint)dc << 14);
            }
        }
        return;
    }

    // ---------------- mm1m ----------------
    int t    = threadIdx.x;
    int w    = t >> 6;
    int lane = t & 63;
    int m    = lane & 15;
    int quad = lane >> 4;
    int n0   = blockIdx.x * 128;

    f32x4 acc[2][8];
#pragma unroll
    for (int rt = 0; rt < 2; rt++)
#pragma unroll
        for (int ct = 0; ct < 8; ct++) acc[rt][ct] = (f32x4){0.f, 0.f, 0.f, 0.f};

#pragma unroll 1
    for (int kc = 0; kc < 8; kc++) {
        int k0 = kc * 32;
        const ushort* __restrict__ A = (k0 < 128) ? hb : nbb;
        int ka = k0 & 127;
        __syncthreads();
#pragma unroll
        for (int i = 0; i < 2; i++) {
            int linear = i * 256 + t;       // 0..511
            int row = linear >> 2;
            int q   = linear & 3;
            int nn = n0 + row;
            uint4 v = make_uint4(0u, 0u, 0u, 0u);
            if (nn < N) v = *(const uint4*)(A + (size_t)nn * D + ka + q * 8);
            *(uint4*)(&As[row * LDA + q * 8]) = v;
        }
#pragma unroll
        for (int i = 0; i < 2; i++) {
            int linear = i * 256 + t;
            int col = linear >> 2;
            int q   = linear & 3;
            uint4 v = *(const uint4*)(wT + (size_t)col * 256 + k0 + q * 8);
            *(uint4*)(&Bs[col * LDA + q * 8]) = v;
        }
        __syncthreads();
        short8 af[2], bf[8];
#pragma unroll
        for (int rt = 0; rt < 2; rt++)
            af[rt] = *(const short8*)(&As[(w * 32 + rt * 16 + m) * LDA + quad * 8]);
#pragma unroll
        for (int ct = 0; ct < 8; ct++)
            bf[ct] = *(const short8*)(&Bs[(ct * 16 + m) * LDA + quad * 8]);
#pragma unroll
        for (int rt = 0; rt < 2; rt++)
#pragma unroll
            for (int ct = 0; ct < 8; ct++)
                acc[rt][ct] = __builtin_amdgcn_mfma_f32_16x16x32_bf16(
                    af[rt], bf[ct], acc[rt][ct], 0, 0, 0);
    }
#pragma unroll
    for (int ct = 0; ct < 8; ct++) {
        float bias = b[ct * 16 + m];
#pragma unroll
        for (int rt = 0; rt < 2; rt++) {
#pragma unroll
            for (int r = 0; r < 4; r++) {
                int n = n0 + w * 32 + rt * 16 + quad * 4 + r;
                if (n < N)
                    x1b[(size_t)n * D + ct * 16 + m] =
                        f2b(fmaxf(acc[rt][ct][r] + bias, 0.f));
            }
        }
    }
}

// ===================== dispatch 5: ws2 | gsum1 ==============================
// ws2 (blocks [0,WSB)), 1024 threads = 16 waves (4/SIMD for latency hiding):
//   1) build wcT[64][256] f32 in LDS from part2 records (LDS atomics)
//   2) split into bf16 hi+lo (exactness-preserving), swizzled layout
//   3) transpose-stage x1 bucket slice (swizzled; write pattern ~2-way banks)
//   4) MFMA: 16 waves = 4 g-strips x 4 d-strips; 32 MFMA/wave
//   5) store per-block partial tile P[b][64*128] (no global atomics)
// gsum1 (blocks [WSB, WSB+128)): per-graph x1 sums into S1.

__global__ __launch_bounds__(1024, 4) void k_wg(
    const uint* __restrict__ ebuf2, const int* __restrict__ bcount2,
    const ushort* __restrict__ x1b, const int* __restrict__ gstart,
    float* __restrict__ S1, float* __restrict__ P, int N, int WSB) {
    __shared__ __align__(16) char smem[131072];   // 128 KiB

    if (blockIdx.x >= WSB) {
        // ---------------- gsum1 ----------------
        int b2 = blockIdx.x - WSB;    // 0..127
        int g  = b2 >> 1;
        int ch = b2 & 1;
        int r0 = gstart[g], r1 = gstart[g + 1];
        int len = r1 - r0;
        if (len <= 0) return;
        int L = (len + 1) >> 1;
        int a = r0 + ch * L;
        int bnd = min(a + L, r1);
        if (a >= bnd) return;
        int rp = threadIdx.x >> 6;    // 0..15 row phase
        int cp = threadIdx.x & 63;    // col pair
        float ax = 0.f, ay = 0.f;
        const uint* __restrict__ M = (const uint*)x1b;
        for (int n = a + rp; n < bnd; n += 16) {
            uint v = M[(size_t)n * 64 + cp];
            ax += __uint_as_float(v << 16);
            ay += __uint_as_float(v & 0xffff0000u);
        }
        atomicAdd(&S1[g * D + cp * 2], ax);
        atomicAdd(&S1[g * D + cp * 2 + 1], ay);
        return;
    }

    // ---------------- ws2 ----------------
    float*  lwcT = (float*)smem;             // [64][256] f32 (build phase)
    ushort* lxT  = (ushort*)smem;            // [128][256] u16 swz (overwrites lwcT)
    ushort* lwcb = (ushort*)(smem + 65536);  // [64][256] u16 swz (hi)
    ushort* lwlo = (ushort*)(smem + 98304);  // [64][256] u16 swz (lo)

    int b = blockIdx.x, t = threadIdx.x;
    int n0 = b << 8;

    for (int i = t; i < 16384; i += 1024) lwcT[i] = 0.f;
    __syncthreads();

    int cnt = bcount2[b];
    if (cnt > CAP) cnt = CAP;
    const uint* __restrict__ eb = ebuf2 + (size_t)b * CAP;
    for (int i = t; i < cnt; i += 1024) {
        uint r = eb[i];
        int sl = (int)(r & 255u);
        int g  = (int)((r >> 8) & 63u);
        int dc = (int)((r >> 14) & 127u);
        float id = 1.0f / (float)(dc > 1 ? dc : 1);   // == invdeg[dst] exactly
        atomicAdd(&lwcT[g * 256 + sl], id);           // bank = sl&31: random, ~2-way
    }
    __syncthreads();

    for (int i = t; i < 16384; i += 1024) {
        int g = i >> 8, sl = i & 255;
        float v = lwcT[i];
        ushort hi = f2b(v);
        float fhi = __uint_as_float((uint)hi << 16);
        ushort lo = f2b(v - fhi);
        int si = swz2i(g, sl);
        lwcb[si] = hi;
        lwlo[si] = lo;
    }
    __syncthreads();   // lwcT fully consumed -> safe to overwrite with lxT

    const uint4* __restrict__ x4 = (const uint4*)x1b;
#pragma unroll 1
    for (int it = 0; it < 4; ++it) {
        int l = it * 1024 + t;
        int n = l >> 4, q = l & 15;
        uint4 v = make_uint4(0u, 0u, 0u, 0u);
        int nn = n0 + n;
        if (nn < N) v = x4[(size_t)nn * 16 + q];
        int d0 = q * 8;
        lxT[swz2i(d0 + 0, n)] = (ushort)(v.x & 0xffffu);
        lxT[swz2i(d0 + 1, n)] = (ushort)(v.x >> 16);
        lxT[swz2i(d0 + 2, n)] = (ushort)(v.y & 0xffffu);
        lxT[swz2i(d0 + 3, n)] = (ushort)(v.y >> 16);
        lxT[swz2i(d0 + 4, n)] = (ushort)(v.z & 0xffffu);
        lxT[swz2i(d0 + 5, n)] = (ushort)(v.z >> 16);
        lxT[swz2i(d0 + 6, n)] = (ushort)(v.w & 0xffffu);
        lxT[swz2i(d0 + 7, n)] = (ushort)(v.w >> 16);
    }
    __syncthreads();

    int wv = t >> 6, lane = t & 63, m = lane & 15, quad = lane >> 4;
    int s  = wv & 3;     // g-strip (16 rows)
    int hs = wv >> 2;    // d-strip (32 cols)
    f32x4 acc[2];
    acc[0] = (f32x4){0.f, 0.f, 0.f, 0.f};
    acc[1] = (f32x4){0.f, 0.f, 0.f, 0.f};

#pragma unroll 1
    for (int k8 = 0; k8 < 8; ++k8) {
        int kc = k8 * 32 + quad * 8;
        int ar = s * 16 + m;
        short8 ahi = *(const short8*)&lwcb[swz2i(ar, kc)];
        short8 alo = *(const short8*)&lwlo[swz2i(ar, kc)];
#pragma unroll
        for (int d2 = 0; d2 < 2; ++d2) {
            short8 bfr = *(const short8*)&lxT[swz2i(hs * 32 + d2 * 16 + m, kc)];
            acc[d2] = __builtin_amdgcn_mfma_f32_16x16x32_bf16(alo, bfr, acc[d2], 0, 0, 0);
            acc[d2] = __builtin_amdgcn_mfma_f32_16x16x32_bf16(ahi, bfr, acc[d2], 0, 0, 0);
        }
    }
    float* __restrict__ Pb = P + (size_t)b * 8192;
#pragma unroll
    for (int d2 = 0; d2 < 2; ++d2) {
#pragma unroll
        for (int r = 0; r < 4; ++r) {
            int g = s * 16 + quad * 4 + r;
            Pb[g * 128 + hs * 32 + d2 * 16 + m] = acc[d2][r];
        }
    }
}

// ===================== dispatch 6: final (P-reduce + tiny matmuls) ==========

__global__ __launch_bounds__(256) void k_final(
    const float* __restrict__ S1, const float* __restrict__ P, int NBLK,
    const int* __restrict__ gstart, const float* __restrict__ W2s,
    const float* __restrict__ W2n, const float* __restrict__ b2,
    const float* __restrict__ Wc, const float* __restrict__ bc,
    float* __restrict__ out) {
    __shared__ float s1[D], s2[2][D], hg[D];
    int g = blockIdx.x, t = threadIdx.x;
    int c = t & 127, hh = t >> 7;
    // S2[g][c] = sum_b P[b][g*128+c]  (split over hh, 4-way unrolled for MLP)
    const float* __restrict__ Pg = P + (size_t)g * 128 + c;
    float a0 = 0.f, a1 = 0.f, a2 = 0.f, a3 = 0.f;
    int bb = hh;
    for (; bb + 6 < NBLK; bb += 8) {
        a0 += Pg[(size_t)bb * 8192];
        a1 += Pg[(size_t)(bb + 2) * 8192];
        a2 += Pg[(size_t)(bb + 4) * 8192];
        a3 += Pg[(size_t)(bb + 6) * 8192];
    }
    for (; bb < NBLK; bb += 2) a0 += Pg[(size_t)bb * 8192];
    s2[hh][c] = a0 + a1 + a2 + a3;
    if (hh == 0) s1[c] = S1[g * D + c];
    __syncthreads();
    if (t < 128) s2[0][c] += s2[1][c];
    __syncthreads();
    if (t < 128) {
        float acc = 0.f;
#pragma unroll 8
        for (int k = 0; k < D; k++) {
            acc = fmaf(s1[k], W2s[k * D + c], acc);
            acc = fmaf(s2[0][k], W2n[k * D + c], acc);
        }
        int cnt = gstart[g + 1] - gstart[g];
        hg[c] = (cnt > 0) ? (acc / (float)cnt + b2[c]) : 0.f;
    }
    __syncthreads();
    if (t < N_CLS) {
        float o = bc[t];
        for (int k = 0; k < D; k++) o = fmaf(hg[k], Wc[k * N_CLS + t], o);
        out[g * N_CLS + t] = o;
    }
}

// ===================== launch ===============================================

extern "C" void kernel_launch(void* const* d_in, const int* in_sizes, int n_in,
                              void* d_out, int out_size, void* d_ws, size_t ws_size,
                              hipStream_t stream) {
    const float* h   = (const float*)d_in[0];
    const int*   src = (const int*)d_in[1];
    const int*   dst = (const int*)d_in[2];
    const int*   gid = (const int*)d_in[3];
    const float* W1s = (const float*)d_in[5];
    const float* W1n = (const float*)d_in[6];
    const float* b1  = (const float*)d_in[7];
    const float* W2s = (const float*)d_in[8];
    const float* W2n = (const float*)d_in[9];
    const float* b2  = (const float*)d_in[10];
    const float* Wc  = (const float*)d_in[11];
    const float* bc  = (const float*)d_in[12];
    float* out = (float*)d_out;

    const int N = in_sizes[0] / D;  // 100000
    const int E = in_sizes[1];      // 1600000
    const int NB = (N + 255) >> 8;  // 391 buckets

    char* w = (char*)d_ws;
    size_t off = 0;
    auto alloc = [&](size_t elems) -> void* {   // elems are 4-byte units
        void* p = w + off;
        off += elems * 4;
        return p;
    };
    // zero-initialized region first (one memset)
    float* S1      = (float*)alloc((size_t)N_GRAPHS * D);
    int*   bcount  = (int*)alloc(512);
    int*   bcount2 = (int*)alloc(512);
    size_t zero_bytes = off;
    int*   deg    = (int*)alloc(N);
    float* invdeg = (float*)alloc(N);
    int*   gstart = (int*)alloc(128);
    int*   csrf   = (int*)alloc((size_t)N * SLOTS);   // 19.2 MB padded CSR
    ushort* fb    = (ushort*)alloc((size_t)N * 64);   // bf16 [N,128] h
    ushort* nbb   = (ushort*)alloc((size_t)N * 64);   // bf16 [N,128] neigh1
    ushort* x1b   = (ushort*)alloc((size_t)N * 64);   // bf16 [N,128] x1
    ushort* wT    = (ushort*)alloc(16384);            // bf16 [128 cols][256 k]
    // aliases (dead-buffer reuse, no workspace growth):
    uint*  ebuf  = (uint*)nbb;   // dst-buckets: dead once k_aggb writes nbb
    uint*  ebuf2 = (uint*)csrf;  // src-buckets: csrf dead after k_aggb
    float* P     = (float*)fb;   // [NB][64*128] partials: fb dead after k_mmp2
    (void)ws_size;

    hipMemsetAsync(d_ws, 0, zero_bytes, stream);

    int t4 = N * 32;                   // float4 count of [N,128] f32
    int CB = (t4 + 255) / 256;         // cast blocks
    int MMB = (N + 127) / 128;         // mm1m blocks

    // 1: part | castw | gbound | cast
    k_boot<<<256 + 128 + 1 + CB, 256, 0, stream>>>(
        h, fb, W1s, W1n, wT, gid, gstart, src, dst, bcount, ebuf, E, NB, N, t4);
    // 2: CSR build
    k_bucket<<<NB, 1024, 0, stream>>>(ebuf, bcount, csrf, deg, invdeg, N);
    // 3: neighbor-mean gather (layer 1)
    k_aggb<<<(N + 3) / 4, 256, 0, stream>>>(fb, deg, csrf, invdeg, nbb, N);
    // 4: mm1m | part2 (csrf dead -> ebuf2 in its space)
    k_mmp2<<<MMB + 256, 256, 0, stream>>>(
        fb, nbb, wT, b1, x1b, N, MMB, src, dst, gid, deg, bcount2, ebuf2, E, NB);
    // 5: ws2 (MFMA collapse of layer-2 agg, partials to P) | gsum1
    k_wg<<<NB + 128, 1024, 0, stream>>>(
        ebuf2, bcount2, x1b, gstart, S1, P, N, NB);
    // 6: final (P reduction + output head)
    k_final<<<N_GRAPHS, 256, 0, stream>>>(
        S1, P, NB, gstart, W2s, W2n, b2, Wc, bc, out);
}